// Round 9
// baseline (308.313 us; speedup 1.0000x reference)
//
#include <hip/hip_runtime.h>

// VectorQuantizer: B=16,T=8192,D=64,K=1024
// Round 17: ABLATION round. 8 structurally distinct kernels (r8-r16) all
// land at ~80us / ~640 TF effective; every cycle model failed by 2-4x and
// gfx950 derived counters are gfx94x-formula fallbacks (untrustworthy).
// Per methodology (m164-166): template-ablate the phases, read raw per-
// dispatch dur_us. ab<0>=skeleton(stage+LOADW+x-prep), ab<1>=+CHAINS,
// ab<2>=+TRACK(no epilogue), then the UNCHANGED r16 kernel runs last and
// overwrites all output (absmax stays 0). Deltas decompose the wall.
#define MTOK  131072
#define DIMD  64
#define KCODE 1024
#define TPB   512        // tokens per block = 8 waves x 64 tokens

typedef __bf16 bf16x8 __attribute__((ext_vector_type(8)));
typedef float  f32x4  __attribute__((ext_vector_type(4)));

__device__ __forceinline__ f32x4 mfma16(bf16x8 a, bf16x8 b, f32x4 c) {
    return __builtin_amdgcn_mfma_f32_16x16x32_bf16(a, b, c, 0, 0, 0);
}

__device__ __forceinline__ void g2l16(const void* g, void* l) {
    __builtin_amdgcn_global_load_lds(
        (const __attribute__((address_space(1))) unsigned int*)g,
        (__attribute__((address_space(3))) unsigned int*)l, 16, 0, 0);
}

// ---- prep: pack W into MFMA-fragment order + e2 tables (r5-verified) ----
__global__ __launch_bounds__(256) void prep_kernel(
    const float* __restrict__ w, __bf16* __restrict__ wpk,
    float* __restrict__ e2n, float* __restrict__ e2) {
    int b   = blockIdx.x;
    int tid = threadIdx.x;
    if (b < 64) {
        int cb  = b;
        int win = tid >> 6, lane = tid & 63;
        int q = lane >> 4, m = lane & 15;
        int k = cb * 16 + m;
        int d0 = (win & 1) * 32 + q * 8;
        const float* src = w + (size_t)k * DIMD + d0;
        float4 v0 = *(const float4*)(src);
        float4 v1 = *(const float4*)(src + 4);
        float f[8] = {v0.x, v0.y, v0.z, v0.w, v1.x, v1.y, v1.z, v1.w};
        bf16x8 o;
#pragma unroll
        for (int j = 0; j < 8; ++j) {
            __bf16 h = (__bf16)f[j];
            o[j] = (win < 2) ? h : (__bf16)(f[j] - (float)h);
        }
        *(bf16x8*)(wpk + ((size_t)(cb * 4 + win) * 64 + lane) * 8) = o;
    } else {
        int k2 = (b - 64) * 256 + tid;
        const float4* row = (const float4*)(w + (size_t)k2 * DIMD);
        float s = 0.f;
#pragma unroll
        for (int i = 0; i < 16; ++i) {
            float4 v = row[i];
            s = fmaf(v.x, v.x, s); s = fmaf(v.y, v.y, s);
            s = fmaf(v.z, v.z, s); s = fmaf(v.w, v.w, s);
        }
        e2[k2]  = s;
        e2n[k2] = -0.5f * s;
    }
}

#define LOADW(S, WB, L)                                        \
    W##S##0 = *(const bf16x8*)((WB) + (L) * 2048 + 0);         \
    W##S##1 = *(const bf16x8*)((WB) + (L) * 2048 + 512);       \
    W##S##2 = *(const bf16x8*)((WB) + (L) * 2048 + 1024);      \
    W##S##3 = *(const bf16x8*)((WB) + (L) * 2048 + 1536);      \
    E##S    = *(const f32x4*)&ldsE[(CB0 + (L)) * 16 + q * 4];

#define CHAINS(S)                                              \
    __builtin_amdgcn_s_setprio(1);                             \
    t##S##0 = mfma16(W##S##0, bx[0][0], E##S);                 \
    t##S##1 = mfma16(W##S##0, bx[1][0], E##S);                 \
    t##S##2 = mfma16(W##S##0, bx[2][0], E##S);                 \
    t##S##3 = mfma16(W##S##0, bx[3][0], E##S);                 \
    t##S##0 = mfma16(W##S##1, bx[0][1], t##S##0);              \
    t##S##1 = mfma16(W##S##1, bx[1][1], t##S##1);              \
    t##S##2 = mfma16(W##S##1, bx[2][1], t##S##2);              \
    t##S##3 = mfma16(W##S##1, bx[3][1], t##S##3);              \
    t##S##0 = mfma16(W##S##0, bx[0][2], t##S##0);              \
    t##S##1 = mfma16(W##S##0, bx[1][2], t##S##1);              \
    t##S##2 = mfma16(W##S##0, bx[2][2], t##S##2);              \
    t##S##3 = mfma16(W##S##0, bx[3][2], t##S##3);              \
    t##S##0 = mfma16(W##S##1, bx[0][3], t##S##0);              \
    t##S##1 = mfma16(W##S##1, bx[1][3], t##S##1);              \
    t##S##2 = mfma16(W##S##1, bx[2][3], t##S##2);              \
    t##S##3 = mfma16(W##S##1, bx[3][3], t##S##3);              \
    t##S##0 = mfma16(W##S##2, bx[0][0], t##S##0);              \
    t##S##1 = mfma16(W##S##2, bx[1][0], t##S##1);              \
    t##S##2 = mfma16(W##S##2, bx[2][0], t##S##2);              \
    t##S##3 = mfma16(W##S##2, bx[3][0], t##S##3);              \
    t##S##0 = mfma16(W##S##3, bx[0][1], t##S##0);              \
    t##S##1 = mfma16(W##S##3, bx[1][1], t##S##1);              \
    t##S##2 = mfma16(W##S##3, bx[2][1], t##S##2);              \
    t##S##3 = mfma16(W##S##3, bx[3][1], t##S##3);              \
    __builtin_amdgcn_s_setprio(0);

#define TRACK(S, CBASE)                                        \
    {                                                          \
        f32x4 tt_[4] = {t##S##0, t##S##1, t##S##2, t##S##3};   \
        _Pragma("unroll")                                      \
        for (int tg_ = 0; tg_ < 4; ++tg_) {                    \
            _Pragma("unroll")                                  \
            for (int r_ = 0; r_ < 4; ++r_) {                   \
                float a_ = tt_[tg_][r_];                       \
                int iv_  = (CBASE) + q * 4 + r_;               \
                bool gt_ = a_ > b1[tg_];                       \
                i1[tg_] = gt_ ? iv_ : i1[tg_];                 \
                b2[tg_] = __builtin_amdgcn_fmed3f(a_, b1[tg_], b2[tg_]); \
                b1[tg_] = fmaxf(a_, b1[tg_]);                  \
            }                                                  \
        }                                                      \
    }

// keep-alive helpers (rule #17: consume ALL bytes so loads don't narrow)
#define KEEPW(S)                                               \
    kv += __builtin_bit_cast(f32x4, W##S##0);                  \
    kv += __builtin_bit_cast(f32x4, W##S##1);                  \
    kv += __builtin_bit_cast(f32x4, W##S##2);                  \
    kv += __builtin_bit_cast(f32x4, W##S##3);                  \
    kv += E##S;
#define KEEPT(S)                                               \
    kv += t##S##0; kv += t##S##1; kv += t##S##2; kv += t##S##3;

// ---- ablation kernel: MODE 0 = skeleton, 1 = +chains, 2 = +tracker ----
template <int MODE>
__global__ __launch_bounds__(512, 2) void vq_ab(
    const float* __restrict__ x, const __bf16* __restrict__ wpk,
    const float* __restrict__ e2n_g, float* __restrict__ out) {

    __shared__ __align__(16) __bf16 ldsW[2][32768];
    __shared__ __align__(16) float  ldsE[KCODE];

    const int tid  = threadIdx.x;
    const int blk  = blockIdx.x;
    const int lane = tid & 63;
    const int wv   = tid >> 6;
    const int q    = lane >> 4;
    const int m    = lane & 15;
    const size_t tok0 = (size_t)blk * TPB + wv * 64;

    {
        const char* gw = (const char*)wpk + tid * 16;
        char* lw = (char*)&ldsW[0][0] + tid * 16;
#pragma unroll
        for (int j = 0; j < 8; ++j)
            g2l16(gw + j * 8192, lw + j * 8192);
        if (tid < 256)
            g2l16((const char*)e2n_g + tid * 16, (char*)ldsE + tid * 16);
    }

    bf16x8 bx[4][4];
#pragma unroll
    for (int tg = 0; tg < 4; ++tg) {
        const float* xr = x + (tok0 + tg * 16 + m) * DIMD;
#pragma unroll
        for (int h = 0; h < 2; ++h) {
            float4 v0 = *(const float4*)(xr + h * 32 + q * 8);
            float4 v1 = *(const float4*)(xr + h * 32 + q * 8 + 4);
            float f[8] = {v0.x, v0.y, v0.z, v0.w, v1.x, v1.y, v1.z, v1.w};
            bf16x8 hi, lo;
#pragma unroll
            for (int j = 0; j < 8; ++j) {
                __bf16 hh = (__bf16)f[j];
                hi[j] = hh;
                lo[j] = (__bf16)(f[j] - (float)hh);
            }
            bx[tg][h]     = hi;
            bx[tg][2 + h] = lo;
        }
    }

    float b1[4], b2[4]; int i1[4];
#pragma unroll
    for (int tg = 0; tg < 4; ++tg) { b1[tg] = -3e38f; b2[tg] = -3e38f; i1[tg] = 0; }

    f32x4 kv = {0.f, 0.f, 0.f, 0.f};
    if constexpr (MODE == 0) {   // keep x-prep live (unused by loop in MODE 0)
#pragma unroll
        for (int tg = 0; tg < 4; ++tg)
#pragma unroll
            for (int h = 0; h < 4; ++h)
                kv += __builtin_bit_cast(f32x4, bx[tg][h]);
    }

    __syncthreads();

    for (int ch = 0; ch < 4; ++ch) {
        if (ch + 1 < 4) {
            const char* gw = (const char*)wpk + (size_t)(ch + 1) * 65536 + tid * 16;
            char* lw = (char*)&ldsW[(ch + 1) & 1][0] + tid * 16;
#pragma unroll
            for (int j = 0; j < 8; ++j)
                g2l16(gw + j * 8192, lw + j * 8192);
        }

        const __bf16* wb = &ldsW[ch & 1][0] + lane * 8;
        const int CB0 = ch * 16;

        bf16x8 WA0, WA1, WA2, WA3, WB0, WB1, WB2, WB3;
        f32x4  EA, EB, tA0, tA1, tA2, tA3, tB0, tB1, tB2, tB3;

        LOADW(A, wb, 0);
        if constexpr (MODE >= 1) { CHAINS(A); }
        if constexpr (MODE == 0) { KEEPW(A); }
        if constexpr (MODE == 1) { KEEPT(A); }

        for (int l = 1; l <= 13; l += 2) {
            LOADW(B, wb, l);
            if constexpr (MODE >= 2) TRACK(A, (CB0 + l - 1) * 16);
            if constexpr (MODE >= 1) { CHAINS(B); }
            if constexpr (MODE == 0) { KEEPW(B); }
            if constexpr (MODE == 1) { KEEPT(B); }

            LOADW(A, wb, l + 1);
            if constexpr (MODE >= 2) TRACK(B, (CB0 + l) * 16);
            if constexpr (MODE >= 1) { CHAINS(A); }
            if constexpr (MODE == 0) { KEEPW(A); }
            if constexpr (MODE == 1) { KEEPT(A); }
        }
        LOADW(B, wb, 15);
        if constexpr (MODE >= 2) TRACK(A, (CB0 + 14) * 16);
        if constexpr (MODE >= 1) { CHAINS(B); }
        if constexpr (MODE >= 2) TRACK(B, (CB0 + 15) * 16);
        if constexpr (MODE == 0) { KEEPW(B); }
        if constexpr (MODE == 1) { KEEPT(B); }

        if (ch + 1 < 4)
            __syncthreads();
    }

    // keep-alive final store (overwritten by the real kernel afterwards)
    if constexpr (MODE <= 1) {
        out[tok0 + lane] = kv[0] + kv[1] + kv[2] + kv[3];
    } else {
        out[tok0 + lane] = b1[0] + b2[0] + b1[1] + b2[1] + b1[2] + b2[2]
                         + b1[3] + b2[3] + (float)(i1[0] ^ i1[1] ^ i1[2] ^ i1[3]);
    }
}

// ---- REAL kernel: r16 verbatim (runs last, writes all output) ----
__global__ __launch_bounds__(512, 2) void vq_main(
    const float* __restrict__ x, const float* __restrict__ wfull,
    const __bf16* __restrict__ wpk, const float* __restrict__ e2n_g,
    const float* __restrict__ e2_g, float* __restrict__ out) {

    __shared__ __align__(16) __bf16 ldsW[2][32768];
    __shared__ __align__(16) float  ldsE[KCODE];

    const int tid  = threadIdx.x;
    const int blk  = blockIdx.x;
    const int lane = tid & 63;
    const int wv   = tid >> 6;
    const int q    = lane >> 4;
    const int m    = lane & 15;
    const size_t tok0 = (size_t)blk * TPB + wv * 64;

    {
        const char* gw = (const char*)wpk + tid * 16;
        char* lw = (char*)&ldsW[0][0] + tid * 16;
#pragma unroll
        for (int j = 0; j < 8; ++j)
            g2l16(gw + j * 8192, lw + j * 8192);
        if (tid < 256)
            g2l16((const char*)e2n_g + tid * 16, (char*)ldsE + tid * 16);
    }

    bf16x8 bx[4][4];
#pragma unroll
    for (int tg = 0; tg < 4; ++tg) {
        const float* xr = x + (tok0 + tg * 16 + m) * DIMD;
#pragma unroll
        for (int h = 0; h < 2; ++h) {
            float4 v0 = *(const float4*)(xr + h * 32 + q * 8);
            float4 v1 = *(const float4*)(xr + h * 32 + q * 8 + 4);
            float f[8] = {v0.x, v0.y, v0.z, v0.w, v1.x, v1.y, v1.z, v1.w};
            bf16x8 hi, lo;
#pragma unroll
            for (int j = 0; j < 8; ++j) {
                __bf16 hh = (__bf16)f[j];
                hi[j] = hh;
                lo[j] = (__bf16)(f[j] - (float)hh);
            }
            bx[tg][h]     = hi;
            bx[tg][2 + h] = lo;
        }
    }

    float b1[4], b2[4]; int i1[4];
#pragma unroll
    for (int tg = 0; tg < 4; ++tg) { b1[tg] = -3e38f; b2[tg] = -3e38f; i1[tg] = 0; }

    __syncthreads();

    for (int ch = 0; ch < 4; ++ch) {
        if (ch + 1 < 4) {
            const char* gw = (const char*)wpk + (size_t)(ch + 1) * 65536 + tid * 16;
            char* lw = (char*)&ldsW[(ch + 1) & 1][0] + tid * 16;
#pragma unroll
            for (int j = 0; j < 8; ++j)
                g2l16(gw + j * 8192, lw + j * 8192);
        }

        const __bf16* wb = &ldsW[ch & 1][0] + lane * 8;
        const int CB0 = ch * 16;

        bf16x8 WA0, WA1, WA2, WA3, WB0, WB1, WB2, WB3;
        f32x4  EA, EB, tA0, tA1, tA2, tA3, tB0, tB1, tB2, tB3;

        LOADW(A, wb, 0);
        CHAINS(A);

        for (int l = 1; l <= 13; l += 2) {
            LOADW(B, wb, l);
            TRACK(A, (CB0 + l - 1) * 16);
            CHAINS(B);
            LOADW(A, wb, l + 1);
            TRACK(B, (CB0 + l) * 16);
            CHAINS(A);
        }
        LOADW(B, wb, 15);
        TRACK(A, (CB0 + 14) * 16);
        CHAINS(B);
        TRACK(B, (CB0 + 15) * 16);

        if (ch + 1 < 4)
            __syncthreads();
    }

    float B1f[4], B2f[4]; int I1f[4];
#pragma unroll
    for (int tg = 0; tg < 4; ++tg) {
        float B1 = b1[tg], B2 = b2[tg]; int I1 = i1[tg];
#pragma unroll
        for (int mask = 16; mask <= 32; mask <<= 1) {
            float ob1 = __shfl_xor(B1, mask);
            float ob2 = __shfl_xor(B2, mask);
            int   oi  = __shfl_xor(I1, mask);
            bool take = (ob1 > B1) || (ob1 == B1 && oi < I1);
            B2 = fmaxf(fminf(ob1, B1), fmaxf(ob2, B2));
            I1 = take ? oi : I1;
            B1 = fmaxf(ob1, B1);
        }
        B1f[tg] = B1; B2f[tg] = B2; I1f[tg] = I1;
    }

    int myidx;
    {
        int src = lane & 15;
        int v0 = __shfl(I1f[0], src);
        int v1 = __shfl(I1f[1], src);
        int v2 = __shfl(I1f[2], src);
        int v3 = __shfl(I1f[3], src);
        int hi2 = lane >> 4;
        int va = (hi2 & 1) ? v1 : v0;
        int vb = (hi2 & 1) ? v3 : v2;
        myidx = (hi2 & 2) ? vb : va;
    }

#pragma unroll
    for (int tg = 0; tg < 4; ++tg) {
        unsigned long long msk =
            __ballot((lane < 16) && (B1f[tg] - B2f[tg] < 2e-3f));
        while (msk) {
            int mm = __ffsll((unsigned long long)msk) - 1;
            msk &= msk - 1;
            int tloc = tg * 16 + mm;
            const float4* xr = (const float4*)(x + (tok0 + tloc) * DIMD);
            float bv = 3e38f; int bi = 0;
            for (int j = 0; j < 16; ++j) {
                int k = lane * 16 + j;
                const float4* wr = (const float4*)(wfull + (size_t)k * DIMD);
                float s = 0.f;
#pragma unroll
                for (int i = 0; i < 16; ++i) {
                    float4 xv = xr[i], wv4 = wr[i];
                    s = fmaf(xv.x, wv4.x, s); s = fmaf(xv.y, wv4.y, s);
                    s = fmaf(xv.z, wv4.z, s); s = fmaf(xv.w, wv4.w, s);
                }
                float dv = fmaf(-2.f, s, e2_g[k]);
                if (dv < bv) { bv = dv; bi = k; }
            }
#pragma unroll
            for (int mask2 = 1; mask2 <= 32; mask2 <<= 1) {
                float ov = __shfl_xor(bv, mask2);
                int   oi = __shfl_xor(bi, mask2);
                bool take = (ov < bv) || (ov == bv && oi < bi);
                bv = take ? ov : bv;
                bi = take ? oi : bi;
            }
            myidx = (lane == tloc) ? bi : myidx;
        }
    }

    __builtin_nontemporal_store((float)myidx,
                                out + (size_t)MTOK * DIMD + tok0 + lane);

    {
        float* obase = out + tok0 * DIMD;
#pragma unroll
        for (int j = 0; j < 16; ++j) {
            int srcl = j * 4 + (lane >> 4);
            int gi   = __shfl(myidx, srcl);
            f32x4 v = *(const f32x4*)(wfull + (size_t)gi * DIMD + (lane & 15) * 4);
            __builtin_nontemporal_store(v, (f32x4*)(obase + j * 256 + lane * 4));
        }
    }
}

extern "C" void kernel_launch(void* const* d_in, const int* in_sizes, int n_in,
                              void* d_out, int out_size, void* d_ws, size_t ws_size,
                              hipStream_t stream) {
    const float* x = (const float*)d_in[0];
    const float* w = (const float*)d_in[1];
    float* out = (float*)d_out;

    __bf16* wpk = (__bf16*)d_ws;
    float*  e2n = (float*)((char*)d_ws + 262144);
    float*  e2  = (float*)((char*)d_ws + 266240);

    prep_kernel<<<68, 256, 0, stream>>>(w, wpk, e2n, e2);
    // ablation probes (outputs overwritten by vq_main below)
    vq_ab<0><<<MTOK / TPB, 512, 0, stream>>>(x, wpk, e2n, out);
    vq_ab<1><<<MTOK / TPB, 512, 0, stream>>>(x, wpk, e2n, out);
    vq_ab<2><<<MTOK / TPB, 512, 0, stream>>>(x, wpk, e2n, out);
    // real kernel (r16 verbatim) — sole determinant of final output
    vq_main<<<MTOK / TPB, 512, 0, stream>>>(x, w, wpk, e2n, e2, out);
}